// Round 1
// baseline (205.303 us; speedup 1.0000x reference)
//
#include <hip/hip_runtime.h>
#include <hip/hip_cooperative_groups.h>

namespace cg = cooperative_groups;

// Problem constants: B=32, N=1024, F_IN=D=128
#define B    32
#define N    1024
#define FIN  128
#define CHN  16      // chunks per batch
#define ROWS 64      // rows per chunk
#define GRID (B * CHN)   // 512 blocks = exactly 2 per CU on 256 CUs

// ws float offsets
#define OFF_PASUM 0                         // [B][CHN][FIN] column partial sums
#define OFF_P     (B * CHN * FIN)           // [B][N]  p = exp(agg - Mc), 0 for masked
#define OFF_WPART (OFF_P + B * N)           // [B][CHN][FIN] sum of m*p*aq
#define OFF_M     (OFF_WPART + B * CHN * FIN)  // [B][CHN]
#define OFF_L     (OFF_M + B * CHN)
#define OFF_S     (OFF_L + B * CHN)

// Single cooperative kernel: phase A (= old k_asum + tile staging),
// grid sync, phase B (= old k_main minus the aq re-read), grid sync,
// phase C (= old k_final on first 128 blocks). The 64x128 tile stays
// resident in LDS across the syncs, so aq is fetched from HBM ONCE.
// LDS: 32768 + 4096 + 3*512 + 256 + 4 = ~38.7 KB -> 2 blocks/CU by LDS;
// __launch_bounds__(256,2) caps VGPR<=128 -> co-residency guaranteed.
__global__ __launch_bounds__(256, 2) void k_fused(
    const float* __restrict__ aq, const float* __restrict__ mask,
    const float* __restrict__ Wq, const float* __restrict__ bq,
    const float* __restrict__ Wk, const float* __restrict__ bk,
    const float* __restrict__ Wv, const float* __restrict__ bv,
    float* __restrict__ ws, float* __restrict__ out)
{
    const int g = blockIdx.x;
    const int b = g >> 4, ch = g & 15;
    const int tid = threadIdx.x, f = tid & 127, h = tid >> 7;

    __shared__ float tile[ROWS * FIN];        // XOR-swizzled, 32 KB
    __shared__ float4 sh4[256];               // 4 KB, aliased as red[256] floats
    float* red = (float*)sh4;
    __shared__ float asum_s[FIN], ksum_s[FIN], u_s[FIN], mp_s[ROWS];
    __shared__ float c_sh;

    // ---------------- Phase A: stage tile into LDS + per-chunk column sums --
    {
        const float4* g4 = (const float4*)aq + ((size_t)b * N + ch * ROWS) * 32;
        float4* t4 = (float4*)tile;
        float4 accv = make_float4(0.f, 0.f, 0.f, 0.f);
        #pragma unroll
        for (int i = 0; i < 8; ++i) {
            float4 v = g4[i * 256 + tid];
            int gg = i * 256 + tid;
            int row = gg >> 5, c4 = gg & 31;
            t4[row * 32 + (c4 ^ (row & 31))] = v;   // swizzle: (r,j)->r*32+(j^(r&31))
            accv.x += v.x; accv.y += v.y; accv.z += v.z; accv.w += v.w;
        }
        sh4[tid] = accv;
        __syncthreads();
        if (tid < 32) {
            float4 r = sh4[tid];
            #pragma unroll
            for (int gr = 1; gr < 8; ++gr) {
                float4 t = sh4[gr * 32 + tid];
                r.x += t.x; r.y += t.y; r.z += t.z; r.w += t.w;
            }
            float4* outp = (float4*)(ws + OFF_PASUM) + (b * CHN + ch) * 32;
            outp[tid] = r;
        }
    }
    cg::this_grid().sync();

    // ---------------- Phase B: prep + agg + chunk stats + wpart -------------
    {
        float a = 0.f;
        #pragma unroll
        for (int c = 0; c < 8; ++c)
            a += ws[OFF_PASUM + (b * CHN + h * 8 + c) * FIN + f];
        red[tid] = a;
    }
    __syncthreads();
    if (tid < FIN) asum_s[f] = red[f] + red[f + 128];
    __syncthreads();
    {
        float ks = 0.f;
        #pragma unroll 8
        for (int i = 0; i < 64; ++i) {
            int fi = h * 64 + i;
            ks += asum_s[fi] * Wk[fi * FIN + f];      // coalesced over f
        }
        red[tid] = ks;
    }
    __syncthreads();
    if (tid < FIN) ksum_s[f] = red[f] + red[f + 128] + 1024.f * bk[f];
    __syncthreads();
    {
        float uu = 0.f;
        #pragma unroll 8
        for (int i = 0; i < 64; ++i) {
            int d = h * 64 + i;
            uu += Wq[f * FIN + d] * ksum_s[d];        // per-thread sequential rows
        }
        red[tid] = uu;
    }
    __syncthreads();
    if (tid < FIN) u_s[f] = red[f] + red[f + 128];
    if (tid < 64) {
        float cc = bq[tid] * ksum_s[tid] + bq[tid + 64] * ksum_s[tid + 64];
        #pragma unroll
        for (int off = 32; off > 0; off >>= 1) cc += __shfl_xor(cc, off);
        if (tid == 0) c_sh = cc;
    }
    __syncthreads();   // u_s/c_sh ready; tile is already resident from phase A

    // ---- all 64 row-dots in parallel: thread (r = tid&63, q = tid>>6)
    {
        const int r = tid & 63, q = tid >> 6;
        const float4* t4 = (const float4*)tile;
        const float4* u4 = (const float4*)u_s;
        float acc = 0.f;
        #pragma unroll
        for (int jj = 0; jj < 8; ++jj) {
            int j = q * 8 + jj;
            float4 a = t4[r * 32 + (j ^ (r & 31))];
            float4 uu = u4[j];                        // wave-uniform
            acc += a.x * uu.x + a.y * uu.y + a.z * uu.z + a.w * uu.w;
        }
        red[tid] = acc;
    }
    __syncthreads();
    if (tid < ROWS) {
        const float dkc = 0.08838834764831845f;       // 128^-0.5
        float dot = red[tid] + red[tid + 64] + red[tid + 128] + red[tid + 192];
        float m = mask[b * N + ch * ROWS + tid];      // coalesced
        float raw = dkc * (dot + c_sh);
        float aggv = m * raw + (1.f - m) * (-1e9f);
        float Mc = aggv;
        #pragma unroll
        for (int off = 32; off > 0; off >>= 1) Mc = fmaxf(Mc, __shfl_xor(Mc, off));
        float p = __expf(aggv - Mc);                  // masked rows -> exact 0
        float mp = m * p;
        ws[OFF_P + b * N + ch * ROWS + tid] = p;
        mp_s[tid] = mp;
        float Lc = p, Sc = mp;
        #pragma unroll
        for (int off = 32; off > 0; off >>= 1) {
            Lc += __shfl_xor(Lc, off);
            Sc += __shfl_xor(Sc, off);
        }
        if (tid == 0) {
            ws[OFF_M + b * CHN + ch] = Mc;
            ws[OFF_L + b * CHN + ch] = Lc;
            ws[OFF_S + b * CHN + ch] = Sc;
        }
    }
    __syncthreads();
    // ---- weighted column sums: wpart[f] = sum_r mp[r] * aq[r][f]
    {
        float w = 0.f;
        #pragma unroll 8
        for (int i = 0; i < 32; ++i) {
            int r = h * 32 + i;
            w += mp_s[r] * tile[r * FIN + ((((f >> 2) ^ (r & 31)) << 2) | (f & 3))];
        }
        red[tid] = w;
    }
    __syncthreads();
    if (tid < FIN)
        ws[OFF_WPART + (b * CHN + ch) * FIN + f] = red[f] + red[f + 128];

    cg::this_grid().sync();

    // ---------------- Phase C: cross-chunk combine + attn + context ---------
    if (g >= B * 4) return;   // after last sync: safe to retire extra blocks
    {
        const int bb = g >> 2, sub = g & 3;
        float M = -3.0e38f;
        #pragma unroll
        for (int c = 0; c < CHN; ++c) M = fmaxf(M, ws[OFF_M + bb * CHN + c]);
        float Em[CHN], L = 0.f, S = 0.f;
        #pragma unroll
        for (int c = 0; c < CHN; ++c) {
            float e = __expf(ws[OFF_M + bb * CHN + c] - M);
            Em[c] = e;
            L += e * ws[OFF_L + bb * CHN + c];
            S += e * ws[OFF_S + bb * CHN + c];
        }
        const float invL = 1.f / L;
        // attn = p * Em[chunk] * invL  (one row per thread, coalesced)
        {
            int n = sub * 256 + tid;               // chunk = sub*4 + (tid>>6)
            out[bb * N + n] = ws[OFF_P + bb * N + n] * Em[sub * 4 + (tid >> 6)] * invL;
        }
        if (sub != 0) return;
        // context (block-uniform path: all 256 threads participate in syncs)
        float* wsh = u_s;                          // reuse LDS
        {
            float w = 0.f;
            #pragma unroll
            for (int c = 0; c < 8; ++c)
                w += Em[h * 8 + c] * ws[OFF_WPART + (bb * CHN + h * 8 + c) * FIN + f];
            red[tid] = w;
        }
        __syncthreads();
        if (tid < FIN) wsh[f] = red[f] + red[f + 128];
        __syncthreads();
        {
            float ctx = 0.f;
            #pragma unroll 8
            for (int i = 0; i < 64; ++i) {
                int fi = h * 64 + i;
                ctx += wsh[fi] * Wv[fi * FIN + f];    // coalesced over f
            }
            red[tid] = ctx;
        }
        __syncthreads();
        if (tid < FIN)
            out[B * N + bb * FIN + f] = (red[f] + red[f + 128]) * invL + S * invL * bv[f];
    }
}

extern "C" void kernel_launch(void* const* d_in, const int* in_sizes, int n_in,
                              void* d_out, int out_size, void* d_ws, size_t ws_size,
                              hipStream_t stream) {
    const float* aq   = (const float*)d_in[0];
    const float* mask = (const float*)d_in[1];
    const float* Wq   = (const float*)d_in[2];
    const float* bq   = (const float*)d_in[3];
    const float* Wk   = (const float*)d_in[4];
    const float* bk   = (const float*)d_in[5];
    const float* Wv   = (const float*)d_in[6];
    const float* bv   = (const float*)d_in[7];
    float* ws  = (float*)d_ws;
    float* out = (float*)d_out;

    void* args[] = {&aq, &mask, &Wq, &bq, &Wk, &bk, &Wv, &bv, &ws, &out};
    hipLaunchCooperativeKernel((const void*)k_fused, dim3(GRID), dim3(256),
                               args, 0, stream);
}

// Round 2
// 138.895 us; speedup vs baseline: 1.4781x; 1.4781x over previous
//
#include <hip/hip_runtime.h>

// Problem constants: B=32, N=1024, F_IN=D=128
#define B    32
#define N    1024
#define FIN  128
#define CHN  16      // chunks per batch
#define ROWS 64      // rows per chunk
#define GRID (B * CHN)   // 512 blocks

// ws float offsets
#define OFF_PU    0                           // [B][CHN][FIN] partial u = Wq@(Wk@pasum)
#define OFF_PC    (B * CHN * FIN)             // [B][CHN]   partial c = bq . pksum
#define OFF_P     (OFF_PC + B * CHN)          // [B][N]     p = exp(agg - Mc), 0 for masked
#define OFF_WPART (OFF_P + B * N)             // [B][CHN][FIN] sum of m*p*aq
#define OFF_M     (OFF_WPART + B * CHN * FIN) // [B][CHN]
#define OFF_L     (OFF_M + B * CHN)
#define OFF_S     (OFF_L + B * CHN)
#define OFF_CNT   (OFF_S + B * CHN)           // [B] uint arrival counters (zeroed by K1)

// ---------------- K1: per-chunk column sums + partial prep ------------------
// pasum_ch[f] = sum_{r in chunk} aq[r][f]           (LDS only)
// pksum_ch[f] = sum_fi pasum_ch[fi]*Wk[fi][f]  (+1024*bk folded into ch==0)
// pu_ch[f]    = sum_d  Wq[f][d]*pksum_ch[d]         -> ws
// pc_ch       = bq . pksum_ch                       -> ws
// Linear in pasum, so summing partials over chunks reproduces ksum/u/c.
// K1 is HBM-bound (reads aq once); the two GEMVs hide under the loads.
__global__ __launch_bounds__(256) void k_pre(const float* __restrict__ aq,
                                             const float* __restrict__ Wq,
                                             const float* __restrict__ bq,
                                             const float* __restrict__ Wk,
                                             const float* __restrict__ bk,
                                             float* __restrict__ ws) {
    const int b = blockIdx.x >> 4, ch = blockIdx.x & 15;
    const int tid = threadIdx.x, f = tid & 127, h = tid >> 7;

    __shared__ float4 sh4[256];               // 4 KB; re-used as float red[] later
    float* red = (float*)sh4;
    __shared__ float asum_s[FIN], pks_s[FIN];

    // zero the arrival counter for K2's last-block handshake (K1 strictly
    // precedes K2 in stream order; kernel-end release makes this visible)
    if (ch == 0 && tid == 0) ((unsigned int*)ws)[OFF_CNT + b] = 0u;

    // ---- column sums of this chunk's 64x128 tile (thread owns col4 = tid&31)
    {
        const float4* g4 = (const float4*)aq + ((size_t)b * N + ch * ROWS) * 32;
        float4 acc = make_float4(0.f, 0.f, 0.f, 0.f);
        #pragma unroll
        for (int i = 0; i < 8; ++i) {
            float4 v = g4[i * 256 + tid];
            acc.x += v.x; acc.y += v.y; acc.z += v.z; acc.w += v.w;
        }
        sh4[tid] = acc;
        __syncthreads();
        if (tid < 32) {
            float4 r = sh4[tid];
            #pragma unroll
            for (int gr = 1; gr < 8; ++gr) {
                float4 t = sh4[gr * 32 + tid];
                r.x += t.x; r.y += t.y; r.z += t.z; r.w += t.w;
            }
            ((float4*)asum_s)[tid] = r;
        }
    }
    __syncthreads();
    // ---- GEMV1: pksum = asum @ Wk   (coalesced over f)
    {
        float ks = 0.f;
        #pragma unroll 8
        for (int i = 0; i < 64; ++i) {
            int fi = h * 64 + i;
            ks += asum_s[fi] * Wk[fi * FIN + f];
        }
        red[tid] = ks;
    }
    __syncthreads();
    if (tid < FIN) {
        float pk = red[f] + red[f + 128];
        if (ch == 0) pk += 1024.f * bk[f];    // fold the bias term exactly once
        pks_s[f] = pk;
    }
    __syncthreads();
    // ---- GEMV2: pu[f] = Wq[f][:] . pksum   (L1/L2-amortized rows)
    {
        float uu = 0.f;
        #pragma unroll 8
        for (int i = 0; i < 64; ++i) {
            int d = h * 64 + i;
            uu += Wq[f * FIN + d] * pks_s[d];
        }
        red[tid] = uu;
    }
    __syncthreads();
    if (tid < FIN)
        ws[OFF_PU + (b * CHN + ch) * FIN + f] = red[f] + red[f + 128];
    // ---- pc = bq . pksum
    if (tid < 64) {
        float cc = bq[tid] * pks_s[tid] + bq[tid + 64] * pks_s[tid + 64];
        #pragma unroll
        for (int off = 32; off > 0; off >>= 1) cc += __shfl_xor(cc, off);
        if (tid == 0) ws[OFF_PC + b * CHN + ch] = cc;
    }
}

// ---------------- K2: agg + chunk stats + wpart + last-block finalize -------
__global__ __launch_bounds__(256) void k_main(
    const float* __restrict__ aq, const float* __restrict__ mask,
    const float* __restrict__ Wv, const float* __restrict__ bv,
    float* __restrict__ ws, float* __restrict__ out)
{
    const int b = blockIdx.x >> 4, ch = blockIdx.x & 15;
    const int tid = threadIdx.x, f = tid & 127, h = tid >> 7;

    __shared__ float tile[ROWS * FIN];        // XOR-swizzled, 32 KB
    __shared__ float red[256];
    __shared__ float u_s[FIN], mp_s[ROWS];
    __shared__ float c_sh;
    __shared__ int   last_s;

    // Issue the tile staging loads FIRST (aq is L2-hot from K1); they drain
    // while the short prep combine runs.
    float4 stage[8];
    const float4* g4 = (const float4*)aq + ((size_t)b * N + ch * ROWS) * 32;
    #pragma unroll
    for (int i = 0; i < 8; ++i) stage[i] = g4[i * 256 + tid];

    // ---- prep: u = sum_ch pu_ch ; c = sum_ch pc_ch   (one reduction round)
    {
        float uu = 0.f;
        #pragma unroll
        for (int c = 0; c < 8; ++c)
            uu += ws[OFF_PU + (b * CHN + h * 8 + c) * FIN + f];
        red[tid] = uu;
    }
    float cc = 0.f;
    if (tid < 16) cc = ws[OFF_PC + b * CHN + tid];
    __syncthreads();
    if (tid < FIN) u_s[f] = red[f] + red[f + 128];
    if (tid < 16) {
        #pragma unroll
        for (int off = 8; off > 0; off >>= 1) cc += __shfl_xor(cc, off);
        if (tid == 0) c_sh = cc;
    }
    // ---- commit staged tile (swizzle: float4 (r,j) -> r*32 + (j ^ (r&31)))
    {
        float4* t4 = (float4*)tile;
        #pragma unroll
        for (int i = 0; i < 8; ++i) {
            int g = i * 256 + tid;
            int row = g >> 5, c4 = g & 31;
            t4[row * 32 + (c4 ^ (row & 31))] = stage[i];
        }
    }
    __syncthreads();

    // ---- all 64 row-dots in parallel: thread (r = tid&63, q = tid>>6)
    {
        const int r = tid & 63, q = tid >> 6;
        const float4* t4 = (const float4*)tile;
        const float4* u4 = (const float4*)u_s;
        float acc = 0.f;
        #pragma unroll
        for (int jj = 0; jj < 8; ++jj) {
            int j = q * 8 + jj;
            float4 a = t4[r * 32 + (j ^ (r & 31))];
            float4 uu = u4[j];                        // wave-uniform
            acc += a.x * uu.x + a.y * uu.y + a.z * uu.z + a.w * uu.w;
        }
        red[tid] = acc;
    }
    __syncthreads();
    if (tid < ROWS) {
        const float dkc = 0.08838834764831845f;       // 128^-0.5
        float dot = red[tid] + red[tid + 64] + red[tid + 128] + red[tid + 192];
        float m = mask[b * N + ch * ROWS + tid];      // coalesced
        float raw = dkc * (dot + c_sh);
        float aggv = m * raw + (1.f - m) * (-1e9f);
        float Mc = aggv;
        #pragma unroll
        for (int off = 32; off > 0; off >>= 1) Mc = fmaxf(Mc, __shfl_xor(Mc, off));
        float p = __expf(aggv - Mc);                  // masked rows -> exact 0
        float mp = m * p;
        ws[OFF_P + b * N + ch * ROWS + tid] = p;
        mp_s[tid] = mp;
        float Lc = p, Sc = mp;
        #pragma unroll
        for (int off = 32; off > 0; off >>= 1) {
            Lc += __shfl_xor(Lc, off);
            Sc += __shfl_xor(Sc, off);
        }
        if (tid == 0) {
            ws[OFF_M + b * CHN + ch] = Mc;
            ws[OFF_L + b * CHN + ch] = Lc;
            ws[OFF_S + b * CHN + ch] = Sc;
        }
    }
    __syncthreads();
    // ---- weighted column sums: wpart[f] = sum_r mp[r] * aq[r][f]
    {
        float w = 0.f;
        #pragma unroll 8
        for (int i = 0; i < 32; ++i) {
            int r = h * 32 + i;
            w += mp_s[r] * tile[r * FIN + ((((f >> 2) ^ (r & 31)) << 2) | (f & 3))];
        }
        red[tid] = w;
    }
    __syncthreads();
    if (tid < FIN)
        ws[OFF_WPART + (b * CHN + ch) * FIN + f] = red[f] + red[f + 128];

    // ---- last-block-per-batch handshake (no spinning) ----------------------
    __threadfence();                              // release this block's ws writes
    __syncthreads();
    if (tid == 0) {
        unsigned int old = atomicAdd((unsigned int*)ws + OFF_CNT + b, 1u);
        last_s = (old == (unsigned)(CHN - 1));
    }
    __syncthreads();
    if (!last_s) return;
    __threadfence();                              // acquire other blocks' writes

    // ---------------- finalize: cross-chunk combine + attn + context --------
    float M = -3.0e38f;
    #pragma unroll
    for (int c = 0; c < CHN; ++c) M = fmaxf(M, ws[OFF_M + b * CHN + c]);
    float L = 0.f, S = 0.f;
    #pragma unroll
    for (int c = 0; c < CHN; ++c) {
        float e = __expf(ws[OFF_M + b * CHN + c] - M);
        L += e * ws[OFF_L + b * CHN + c];
        S += e * ws[OFF_S + b * CHN + c];
    }
    const float invL = 1.f / L;
    // attn = p * exp(Mc - M) * invL   (4 rows per thread, float4-coalesced;
    // recompute the chunk factor to avoid a runtime-indexed register array)
    {
        float4 p4 = ((const float4*)(ws + OFF_P + b * N))[tid];
        float sc = __expf(ws[OFF_M + b * CHN + (tid >> 4)] - M) * invL;
        float4 o4 = make_float4(p4.x * sc, p4.y * sc, p4.z * sc, p4.w * sc);
        ((float4*)(out + b * N))[tid] = o4;
    }
    // context
    {
        float w = 0.f;
        #pragma unroll
        for (int c = 0; c < 8; ++c) {
            float e = __expf(ws[OFF_M + b * CHN + h * 8 + c] - M);
            w += e * ws[OFF_WPART + (b * CHN + h * 8 + c) * FIN + f];
        }
        red[tid] = w;
    }
    __syncthreads();
    if (tid < FIN) u_s[f] = red[f] + red[f + 128];
    __syncthreads();
    {
        float ctx = 0.f;
        #pragma unroll 8
        for (int i = 0; i < 64; ++i) {
            int fi = h * 64 + i;
            ctx += u_s[fi] * Wv[fi * FIN + f];        // coalesced over f
        }
        red[tid] = ctx;
    }
    __syncthreads();
    if (tid < FIN)
        out[B * N + b * FIN + f] = (red[f] + red[f + 128]) * invL + S * invL * bv[f];
}

extern "C" void kernel_launch(void* const* d_in, const int* in_sizes, int n_in,
                              void* d_out, int out_size, void* d_ws, size_t ws_size,
                              hipStream_t stream) {
    const float* aq   = (const float*)d_in[0];
    const float* mask = (const float*)d_in[1];
    const float* Wq   = (const float*)d_in[2];
    const float* bq   = (const float*)d_in[3];
    const float* Wk   = (const float*)d_in[4];
    const float* bk   = (const float*)d_in[5];
    const float* Wv   = (const float*)d_in[6];
    const float* bv   = (const float*)d_in[7];
    float* ws  = (float*)d_ws;
    float* out = (float*)d_out;

    k_pre <<<GRID, 256, 0, stream>>>(aq, Wq, bq, Wk, bk, ws);
    k_main<<<GRID, 256, 0, stream>>>(aq, mask, Wv, bv, ws, out);
}

// Round 3
// 100.515 us; speedup vs baseline: 2.0425x; 1.3818x over previous
//
#include <hip/hip_runtime.h>

// Problem constants: B=32, N=1024, F_IN=D=128
#define B    32
#define N    1024
#define FIN  128
#define CHN  16      // chunks per batch
#define ROWS 64      // rows per chunk
#define GRID (B * CHN)   // 512 blocks

// ws float offsets
#define OFF_PU    0                           // [B][CHN][FIN] partial u = Wq@(Wk@pasum)
#define OFF_PC    (B * CHN * FIN)             // [B][CHN]   partial c = bq . pksum
#define OFF_P     (OFF_PC + B * CHN)          // [B][N]     p = exp(agg - Mc), 0 for masked
#define OFF_WPART (OFF_P + B * N)             // [B][CHN][FIN] sum of m*p*aq
#define OFF_M     (OFF_WPART + B * CHN * FIN) // [B][CHN]
#define OFF_L     (OFF_M + B * CHN)
#define OFF_S     (OFF_L + B * CHN)

// ---------------- K1: per-chunk column sums + partial prep ------------------
// pasum_ch[f] = sum_{r in chunk} aq[r][f]           (LDS only)
// pksum_ch[f] = sum_fi pasum_ch[fi]*Wk[fi][f]  (+1024*bk folded into ch==0)
// pu_ch[f]    = sum_d  Wq[f][d]*pksum_ch[d]         -> ws
// pc_ch       = bq . pksum_ch                       -> ws
// Linear in pasum, so summing partials over chunks reproduces ksum/u/c.
// K1 is HBM-bound (reads aq once); the two GEMVs hide under the loads.
// NOTE: no cross-block sync anywhere — the kernel boundary is the fence.
// Per-block __threadfence() costs ~60 us on gfx950 (L2 wb/inv per XCD).
__global__ __launch_bounds__(256) void k_pre(const float* __restrict__ aq,
                                             const float* __restrict__ Wq,
                                             const float* __restrict__ bq,
                                             const float* __restrict__ Wk,
                                             const float* __restrict__ bk,
                                             float* __restrict__ ws) {
    const int b = blockIdx.x >> 4, ch = blockIdx.x & 15;
    const int tid = threadIdx.x, f = tid & 127, h = tid >> 7;

    __shared__ float4 sh4[256];               // 4 KB; re-used as float red[] later
    float* red = (float*)sh4;
    __shared__ float asum_s[FIN], pks_s[FIN];

    // ---- column sums of this chunk's 64x128 tile (thread owns col4 = tid&31)
    {
        const float4* g4 = (const float4*)aq + ((size_t)b * N + ch * ROWS) * 32;
        float4 acc = make_float4(0.f, 0.f, 0.f, 0.f);
        #pragma unroll
        for (int i = 0; i < 8; ++i) {
            float4 v = g4[i * 256 + tid];
            acc.x += v.x; acc.y += v.y; acc.z += v.z; acc.w += v.w;
        }
        sh4[tid] = acc;
        __syncthreads();
        if (tid < 32) {
            float4 r = sh4[tid];
            #pragma unroll
            for (int gr = 1; gr < 8; ++gr) {
                float4 t = sh4[gr * 32 + tid];
                r.x += t.x; r.y += t.y; r.z += t.z; r.w += t.w;
            }
            ((float4*)asum_s)[tid] = r;
        }
    }
    __syncthreads();
    // ---- GEMV1: pksum = asum @ Wk   (coalesced over f)
    {
        float ks = 0.f;
        #pragma unroll 8
        for (int i = 0; i < 64; ++i) {
            int fi = h * 64 + i;
            ks += asum_s[fi] * Wk[fi * FIN + f];
        }
        red[tid] = ks;
    }
    __syncthreads();
    if (tid < FIN) {
        float pk = red[f] + red[f + 128];
        if (ch == 0) pk += 1024.f * bk[f];    // fold the bias term exactly once
        pks_s[f] = pk;
    }
    __syncthreads();
    // ---- GEMV2: pu[f] = Wq[f][:] . pksum   (L1/L2-amortized rows)
    {
        float uu = 0.f;
        #pragma unroll 8
        for (int i = 0; i < 64; ++i) {
            int d = h * 64 + i;
            uu += Wq[f * FIN + d] * pks_s[d];
        }
        red[tid] = uu;
    }
    __syncthreads();
    if (tid < FIN)
        ws[OFF_PU + (b * CHN + ch) * FIN + f] = red[f] + red[f + 128];
    // ---- pc = bq . pksum
    if (tid < 64) {
        float cc = bq[tid] * pks_s[tid] + bq[tid + 64] * pks_s[tid + 64];
        #pragma unroll
        for (int off = 32; off > 0; off >>= 1) cc += __shfl_xor(cc, off);
        if (tid == 0) ws[OFF_PC + b * CHN + ch] = cc;
    }
}

// ---------------- K2: combine prep + agg + chunk stats + wpart --------------
__global__ __launch_bounds__(256) void k_main(
    const float* __restrict__ aq, const float* __restrict__ mask,
    float* __restrict__ ws)
{
    const int b = blockIdx.x >> 4, ch = blockIdx.x & 15;
    const int tid = threadIdx.x, f = tid & 127, h = tid >> 7;

    __shared__ float tile[ROWS * FIN];        // XOR-swizzled, 32 KB
    __shared__ float red[256];
    __shared__ float u_s[FIN], mp_s[ROWS];
    __shared__ float c_sh;

    // Issue the tile staging loads FIRST; they drain while the short prep
    // combine runs.
    float4 stage[8];
    const float4* g4 = (const float4*)aq + ((size_t)b * N + ch * ROWS) * 32;
    #pragma unroll
    for (int i = 0; i < 8; ++i) stage[i] = g4[i * 256 + tid];

    // ---- prep: u = sum_ch pu_ch ; c = sum_ch pc_ch   (one reduction round)
    {
        float uu = 0.f;
        #pragma unroll
        for (int c = 0; c < 8; ++c)
            uu += ws[OFF_PU + (b * CHN + h * 8 + c) * FIN + f];
        red[tid] = uu;
    }
    float cc = 0.f;
    if (tid < 16) cc = ws[OFF_PC + b * CHN + tid];
    __syncthreads();
    if (tid < FIN) u_s[f] = red[f] + red[f + 128];
    if (tid < 16) {
        #pragma unroll
        for (int off = 8; off > 0; off >>= 1) cc += __shfl_xor(cc, off);
        if (tid == 0) c_sh = cc;
    }
    // ---- commit staged tile (swizzle: float4 (r,j) -> r*32 + (j ^ (r&31)))
    {
        float4* t4 = (float4*)tile;
        #pragma unroll
        for (int i = 0; i < 8; ++i) {
            int g = i * 256 + tid;
            int row = g >> 5, c4 = g & 31;
            t4[row * 32 + (c4 ^ (row & 31))] = stage[i];
        }
    }
    __syncthreads();

    // ---- all 64 row-dots in parallel: thread (r = tid&63, q = tid>>6)
    {
        const int r = tid & 63, q = tid >> 6;
        const float4* t4 = (const float4*)tile;
        const float4* u4 = (const float4*)u_s;
        float acc = 0.f;
        #pragma unroll
        for (int jj = 0; jj < 8; ++jj) {
            int j = q * 8 + jj;
            float4 a = t4[r * 32 + (j ^ (r & 31))];
            float4 uu = u4[j];                        // wave-uniform
            acc += a.x * uu.x + a.y * uu.y + a.z * uu.z + a.w * uu.w;
        }
        red[tid] = acc;
    }
    __syncthreads();
    if (tid < ROWS) {
        const float dkc = 0.08838834764831845f;       // 128^-0.5
        float dot = red[tid] + red[tid + 64] + red[tid + 128] + red[tid + 192];
        float m = mask[b * N + ch * ROWS + tid];      // coalesced
        float raw = dkc * (dot + c_sh);
        float aggv = m * raw + (1.f - m) * (-1e9f);
        float Mc = aggv;
        #pragma unroll
        for (int off = 32; off > 0; off >>= 1) Mc = fmaxf(Mc, __shfl_xor(Mc, off));
        float p = __expf(aggv - Mc);                  // masked rows -> exact 0
        float mp = m * p;
        ws[OFF_P + b * N + ch * ROWS + tid] = p;
        mp_s[tid] = mp;
        float Lc = p, Sc = mp;
        #pragma unroll
        for (int off = 32; off > 0; off >>= 1) {
            Lc += __shfl_xor(Lc, off);
            Sc += __shfl_xor(Sc, off);
        }
        if (tid == 0) {
            ws[OFF_M + b * CHN + ch] = Mc;
            ws[OFF_L + b * CHN + ch] = Lc;
            ws[OFF_S + b * CHN + ch] = Sc;
        }
    }
    __syncthreads();
    // ---- weighted column sums: wpart[f] = sum_r mp[r] * aq[r][f]
    {
        float w = 0.f;
        #pragma unroll 8
        for (int i = 0; i < 32; ++i) {
            int r = h * 32 + i;
            w += mp_s[r] * tile[r * FIN + ((((f >> 2) ^ (r & 31)) << 2) | (f & 3))];
        }
        red[tid] = w;
    }
    __syncthreads();
    if (tid < FIN)
        ws[OFF_WPART + (b * CHN + ch) * FIN + f] = red[f] + red[f + 128];
}

// ---------------- K3: cross-chunk combine + attn + context ------------------
// grid 128 (= B*4), block 256. Each block handles 256 attn rows; sub==0 also
// computes the context row for its batch.
__global__ __launch_bounds__(256) void k_final(const float* __restrict__ Wv,
                                               const float* __restrict__ bv,
                                               const float* __restrict__ ws,
                                               float* __restrict__ out) {
    const int b = blockIdx.x >> 2, sub = blockIdx.x & 3;
    const int tid = threadIdx.x, f = tid & 127, h = tid >> 7;
    float M = -3.0e38f;
    #pragma unroll
    for (int c = 0; c < CHN; ++c) M = fmaxf(M, ws[OFF_M + b * CHN + c]);
    float Em[CHN], L = 0.f, S = 0.f;
    #pragma unroll
    for (int c = 0; c < CHN; ++c) {
        float e = __expf(ws[OFF_M + b * CHN + c] - M);
        Em[c] = e;
        L += e * ws[OFF_L + b * CHN + c];
        S += e * ws[OFF_S + b * CHN + c];
    }
    const float invL = 1.f / L;
    // attn = p * Em[chunk] * invL  (one row per thread, coalesced)
    {
        int n = sub * 256 + tid;               // chunk = sub*4 + (tid>>6)
        out[b * N + n] = ws[OFF_P + b * N + n] * Em[sub * 4 + (tid >> 6)] * invL;
    }
    if (sub != 0) return;
    // context
    __shared__ float wsh[FIN];
    __shared__ float red[256];
    {
        float w = 0.f;
        #pragma unroll
        for (int c = 0; c < 8; ++c)
            w += Em[h * 8 + c] * ws[OFF_WPART + (b * CHN + h * 8 + c) * FIN + f];
        red[tid] = w;
    }
    __syncthreads();
    if (tid < FIN) wsh[f] = red[f] + red[f + 128];
    __syncthreads();
    {
        float ctx = 0.f;
        #pragma unroll 8
        for (int i = 0; i < 64; ++i) {
            int fi = h * 64 + i;
            ctx += wsh[fi] * Wv[fi * FIN + f];        // coalesced over f
        }
        red[tid] = ctx;
    }
    __syncthreads();
    if (tid < FIN)
        out[B * N + b * FIN + f] = (red[f] + red[f + 128]) * invL + S * invL * bv[f];
}

extern "C" void kernel_launch(void* const* d_in, const int* in_sizes, int n_in,
                              void* d_out, int out_size, void* d_ws, size_t ws_size,
                              hipStream_t stream) {
    const float* aq   = (const float*)d_in[0];
    const float* mask = (const float*)d_in[1];
    const float* Wq   = (const float*)d_in[2];
    const float* bq   = (const float*)d_in[3];
    const float* Wk   = (const float*)d_in[4];
    const float* bk   = (const float*)d_in[5];
    const float* Wv   = (const float*)d_in[6];
    const float* bv   = (const float*)d_in[7];
    float* ws  = (float*)d_ws;
    float* out = (float*)d_out;

    k_pre  <<<GRID,  256, 0, stream>>>(aq, Wq, bq, Wk, bk, ws);
    k_main <<<GRID,  256, 0, stream>>>(aq, mask, ws);
    k_final<<<B * 4, 256, 0, stream>>>(Wv, bv, ws, out);
}